// Round 4
// baseline (1444.432 us; speedup 1.0000x reference)
//
#include <hip/hip_runtime.h>
#include <hip/hip_bf16.h>
#include <stdint.h>

#define F_IN 128
#define F_OUT 64
#define NPB 128            // nodes per bucket (dlo fits 7 bits)
#define CHUNK 8192         // edges per partition block
#define NBUCK_MAX 1024
#define SRC_BITS 17        // src index fits 17 bits (n_nodes <= 131072)

static __device__ __forceinline__ unsigned short f2bf(float f) {
    uint32_t u = __float_as_uint(f);
    u += 0x7FFF + ((u >> 16) & 1);       // RNE to bf16
    return (unsigned short)(u >> 16);
}
static __device__ __forceinline__ float bf2f(unsigned short s) {
    return __uint_as_float((uint32_t)s << 16);
}

// ---------------------------------------------------------------------------
// h = x @ W  (f32 compute, bf16 store). 16 rows/block, thread=(row,col4).
// ---------------------------------------------------------------------------
__global__ __launch_bounds__(256) void gemm_xw(const float* __restrict__ x,
                                               const float* __restrict__ W,
                                               unsigned short* __restrict__ h, int n) {
    __shared__ float Ws[F_IN * F_OUT];          // 32 KB
    __shared__ float Xs[16][F_IN + 4];
    for (int i = threadIdx.x; i < F_IN * F_OUT / 4; i += 256)
        ((float4*)Ws)[i] = ((const float4*)W)[i];
    const int row0 = blockIdx.x * 16;
    for (int i = threadIdx.x; i < 16 * 32; i += 256) {
        int r = i >> 5, c = i & 31;
        if (row0 + r < n)
            *(float4*)&Xs[r][c * 4] = *(const float4*)(x + (size_t)(row0 + r) * F_IN + c * 4);
    }
    __syncthreads();
    const int cg = threadIdx.x & 15;
    const int r  = threadIdx.x >> 4;
    const int row = row0 + r;
    float4 acc = make_float4(0.f, 0.f, 0.f, 0.f);
#pragma unroll
    for (int k = 0; k < F_IN; ++k) {
        float  xv = Xs[r][k];
        float4 wv = ((const float4*)Ws)[k * 16 + cg];
        acc.x = fmaf(xv, wv.x, acc.x);
        acc.y = fmaf(xv, wv.y, acc.y);
        acc.z = fmaf(xv, wv.z, acc.z);
        acc.w = fmaf(xv, wv.w, acc.w);
    }
    if (row < n) {
        ushort4 o;
        o.x = f2bf(acc.x); o.y = f2bf(acc.y); o.z = f2bf(acc.z); o.w = f2bf(acc.w);
        *(ushort4*)(h + (size_t)row * F_OUT + cg * 4) = o;
    }
}

// ---------------------------------------------------------------------------
// Phase A1: per-chunk coarse histogram -> histT[k*nchunk + c]
// ---------------------------------------------------------------------------
__global__ __launch_bounds__(512) void histA(const int* __restrict__ dst,
                                             int* __restrict__ histT,
                                             long nE, int nchunk, int nbuck) {
    __shared__ int cnt[NBUCK_MAX];
    for (int i = threadIdx.x; i < nbuck; i += 512) cnt[i] = 0;
    __syncthreads();
    const long base = (long)blockIdx.x * CHUNK;
    const long end  = base + CHUNK < nE ? base + CHUNK : nE;
    for (long i = base + threadIdx.x; i < end; i += 512)
        atomicAdd(&cnt[dst[i] >> 7], 1);
    __syncthreads();
    for (int k = threadIdx.x; k < nbuck; k += 512)
        histT[(long)k * nchunk + blockIdx.x] = cnt[k];
}

// ---------------------------------------------------------------------------
// Generic exclusive scan over n ints (3 kernels), n <= 1024*1024
// ---------------------------------------------------------------------------
__global__ __launch_bounds__(256) void block_sums(const int* __restrict__ a,
                                                  int* __restrict__ sums, int n) {
    __shared__ int lds[256];
    const int tid = threadIdx.x;
    const int base = blockIdx.x * 1024 + tid * 4;
    int s = 0;
#pragma unroll
    for (int i = 0; i < 4; ++i) s += (base + i < n) ? a[base + i] : 0;
    lds[tid] = s; __syncthreads();
    for (int o = 128; o > 0; o >>= 1) {
        if (tid < o) lds[tid] += lds[tid + o];
        __syncthreads();
    }
    if (tid == 0) sums[blockIdx.x] = lds[0];
}

__global__ __launch_bounds__(1024) void scan_sums(int* __restrict__ sums, int nb) {
    __shared__ int lds[1024];
    const int tid = threadIdx.x;
    int v = (tid < nb) ? sums[tid] : 0;
    lds[tid] = v; __syncthreads();
    for (int o = 1; o < 1024; o <<= 1) {
        int t = (tid >= o) ? lds[tid - o] : 0;
        __syncthreads();
        lds[tid] += t;
        __syncthreads();
    }
    if (tid < nb) sums[tid] = lds[tid] - v;
}

__global__ __launch_bounds__(256) void scan_blocks(const int* __restrict__ a,
                                                   const int* __restrict__ blockoffs,
                                                   int* __restrict__ out, int n) {
    __shared__ int lds[256];
    const int tid = threadIdx.x;
    const int idx = blockIdx.x * 1024 + tid * 4;
    int v[4];
#pragma unroll
    for (int i = 0; i < 4; ++i) v[i] = (idx + i < n) ? a[idx + i] : 0;
    const int tsum = v[0] + v[1] + v[2] + v[3];
    lds[tid] = tsum; __syncthreads();
    for (int o = 1; o < 256; o <<= 1) {
        int t = (tid >= o) ? lds[tid - o] : 0;
        __syncthreads();
        lds[tid] += t;
        __syncthreads();
    }
    int run = lds[tid] - tsum + blockoffs[blockIdx.x];
#pragma unroll
    for (int i = 0; i < 4; ++i) {
        if (idx + i < n) out[idx + i] = run;
        run += v[i];
    }
}

// ---------------------------------------------------------------------------
// Phase A3: partition edges into coarse buckets.
// rec = ew(32) | dlo(7 @ bit17) | src(17). Segments per (bucket,chunk) are
// contiguous (~10 records = 84 B) -> low line amplification.
// ---------------------------------------------------------------------------
__global__ __launch_bounds__(512) void partA(const int* __restrict__ src,
                                             const int* __restrict__ dst,
                                             const float* __restrict__ ew,
                                             const int* __restrict__ scanned,
                                             uint64_t* __restrict__ parr,
                                             long nE, int nchunk, int nbuck) {
    __shared__ int cnt[NBUCK_MAX];
    __shared__ int gbase[NBUCK_MAX];
    const int c = blockIdx.x;
    for (int i = threadIdx.x; i < nbuck; i += 512) {
        cnt[i] = 0;
        gbase[i] = scanned[(long)i * nchunk + c];
    }
    __syncthreads();
    const long base = (long)c * CHUNK;
    const long end  = base + CHUNK < nE ? base + CHUNK : nE;
    for (long i = base + threadIdx.x; i < end; i += 512) {
        const int d = dst[i];
        const int k = d >> 7;
        const int r = atomicAdd(&cnt[k], 1);
        const uint64_t rec = ((uint64_t)__float_as_uint(ew[i]) << 32)
                           | ((uint64_t)(d & (NPB - 1)) << SRC_BITS)
                           | (uint32_t)src[i];
        parr[gbase[k] + r] = rec;
    }
}

// ---------------------------------------------------------------------------
// Aggregate: one block per bucket. acc[128][64] f32 in LDS (32 KB).
// Each wave: lane-parallel 64-record batch load (one coalesced 512B request),
// then readlane-broadcast per record -> 1 VMEM (128B h row) + 1 LDS f32
// atomic per edge. Fused ReLU on the coalesced output write.
// ---------------------------------------------------------------------------
__global__ __launch_bounds__(512) void aggregate(const unsigned short* __restrict__ h,
                                                 const uint2* __restrict__ parr,
                                                 const int* __restrict__ scanned,
                                                 float* __restrict__ out,
                                                 int n, long nE, int nchunk, int nbuck) {
    __shared__ float acc[NPB * F_OUT];   // 32 KB
    const int k    = blockIdx.x;
    const int tid  = threadIdx.x;
    const int lane = tid & 63;
    const int wid  = tid >> 6;

    for (int i = tid; i < NPB * F_OUT; i += 512) acc[i] = 0.f;
    __syncthreads();

    const int rbase = scanned[(long)k * nchunk];
    const int rend  = (k + 1 < nbuck) ? scanned[(long)(k + 1) * nchunk] : (int)nE;
    const int m     = rend - rbase;
    const int nbat  = (m + 63) >> 6;

    for (int b = wid; b < nbat; b += 8) {
        const int cbase = b << 6;
        const int count = (m - cbase) < 64 ? (m - cbase) : 64;
        uint2 rec = make_uint2(0u, 0u);
        if (lane < count) rec = parr[(long)rbase + cbase + lane];
#pragma unroll 4
        for (int j = 0; j < count; ++j) {
            const uint32_t lo = __builtin_amdgcn_readlane(rec.x, j);
            const uint32_t hi = __builtin_amdgcn_readlane(rec.y, j);
            const float    wf = __uint_as_float(hi);
            const int    sidx = (int)(lo & ((1u << SRC_BITS) - 1));
            const int     dlo = (int)((lo >> SRC_BITS) & (NPB - 1));
            const float    hv = bf2f(h[(size_t)sidx * F_OUT + lane]);
            atomicAdd(&acc[dlo * F_OUT + lane], wf * hv);
        }
    }
    __syncthreads();

    const long obase = (long)k * (NPB * F_OUT);
    for (int i = tid; i < NPB * F_OUT; i += 512) {
        const int node = k * NPB + (i >> 6);
        if (node < n) out[obase + i] = fmaxf(acc[i], 0.f);
    }
}

// ---------------------------------------------------------------------------
// Fallback: atomic scatter (reads bf16 h)
// ---------------------------------------------------------------------------
__global__ __launch_bounds__(256) void scatter_edges(const unsigned short* __restrict__ h,
                                                     const float* __restrict__ edge_w,
                                                     const int* __restrict__ src,
                                                     const int* __restrict__ dst,
                                                     float* __restrict__ out, long n_edges) {
    const int lane = threadIdx.x & 63;
    const long wave = ((long)blockIdx.x * blockDim.x + threadIdx.x) >> 6;
    const long nwaves = ((long)gridDim.x * blockDim.x) >> 6;
    for (long e = wave; e < n_edges; e += nwaves) {
        const float v = edge_w[e] * bf2f(h[(size_t)src[e] * F_OUT + lane]);
        atomicAdd(&out[(size_t)dst[e] * F_OUT + lane], v);
    }
}

__global__ __launch_bounds__(256) void relu_inplace(float* __restrict__ out, long n4) {
    long i = (long)blockIdx.x * blockDim.x + threadIdx.x;
    const long stride = (long)gridDim.x * blockDim.x;
    float4* p = (float4*)out;
    for (; i < n4; i += stride) {
        float4 v = p[i];
        v.x = v.x > 0.f ? v.x : 0.f;
        v.y = v.y > 0.f ? v.y : 0.f;
        v.z = v.z > 0.f ? v.z : 0.f;
        v.w = v.w > 0.f ? v.w : 0.f;
        p[i] = v;
    }
}

extern "C" void kernel_launch(void* const* d_in, const int* in_sizes, int n_in,
                              void* d_out, int out_size, void* d_ws, size_t ws_size,
                              hipStream_t stream) {
    const float* x      = (const float*)d_in[0];
    const float* W      = (const float*)d_in[1];
    const float* edge_w = (const float*)d_in[2];
    const int*   src    = (const int*)d_in[3];
    const int*   dst    = (const int*)d_in[4];
    float*       out    = (float*)d_out;

    const int  n_nodes = in_sizes[0] / F_IN;
    const long nE      = (long)in_sizes[2];
    const int  NBUCK   = (n_nodes + NPB - 1) / NPB;
    const int  NCHUNK  = (int)((nE + CHUNK - 1) / CHUNK);
    const long nh      = (long)NBUCK * NCHUNK;
    const int  NB      = (int)((nh + 1023) / 1024);

    size_t off = 0;
    auto seg = [&](size_t bytes) { size_t p = off; off = (off + bytes + 255) & ~(size_t)255; return p; };
    const size_t h_off    = seg((size_t)n_nodes * F_OUT * sizeof(unsigned short));
    const size_t parr_off = seg((size_t)nE * sizeof(uint64_t));
    const size_t hist_off = seg((nh + 1) * sizeof(int));
    const size_t scan_off = seg((nh + 1) * sizeof(int));
    const size_t sums_off = seg(1024 * sizeof(int));
    char* ws = (char*)d_ws;

    unsigned short* h = (unsigned short*)(ws + h_off);
    gemm_xw<<<(n_nodes + 15) / 16, 256, 0, stream>>>(x, W, h, n_nodes);

    if (off <= ws_size && NB <= 1024 && NBUCK <= NBUCK_MAX && n_nodes <= (1 << SRC_BITS)) {
        uint64_t* parr    = (uint64_t*)(ws + parr_off);
        int*      histT   = (int*)(ws + hist_off);
        int*      scanned = (int*)(ws + scan_off);
        int*      sums    = (int*)(ws + sums_off);

        histA<<<NCHUNK, 512, 0, stream>>>(dst, histT, nE, NCHUNK, NBUCK);
        block_sums<<<NB, 256, 0, stream>>>(histT, sums, (int)nh);
        scan_sums<<<1, 1024, 0, stream>>>(sums, NB);
        scan_blocks<<<NB, 256, 0, stream>>>(histT, sums, scanned, (int)nh);
        partA<<<NCHUNK, 512, 0, stream>>>(src, dst, edge_w, scanned, parr, nE, NCHUNK, NBUCK);
        aggregate<<<NBUCK, 512, 0, stream>>>(h, (const uint2*)parr, scanned, out,
                                             n_nodes, nE, NCHUNK, NBUCK);
    } else {
        hipMemsetAsync(d_out, 0, (size_t)out_size * sizeof(float), stream);
        scatter_edges<<<2048, 256, 0, stream>>>(h, edge_w, src, dst, out, nE);
        relu_inplace<<<1024, 256, 0, stream>>>(out, (long)out_size / 4);
    }
}